// Round 9
// baseline (921.780 us; speedup 1.0000x reference)
//
#include <hip/hip_runtime.h>
#include <hip/hip_fp8.h>
#include <stdint.h>

#define NN 12288
#define IND 512
#define H1D 256
#define H2D 128

using bf16x8 = __attribute__((ext_vector_type(8))) short;
using f32x4  = __attribute__((ext_vector_type(4))) float;
using u32x4  = __attribute__((ext_vector_type(4))) unsigned int;

__device__ __forceinline__ unsigned short f2bf(float f){
  unsigned int u = __float_as_uint(f);
  return (unsigned short)((u + 0x7fffu + ((u >> 16) & 1u)) >> 16);
}
__device__ __forceinline__ float bf2f(unsigned short h){
  return __uint_as_float(((unsigned int)h) << 16);
}
__device__ __forceinline__ void gload_lds16(const void* g, void* l){
  __builtin_amdgcn_global_load_lds(
      (const __attribute__((address_space(1))) unsigned int*)(uintptr_t)g,
      (__attribute__((address_space(3))) unsigned int*)(unsigned int)(uintptr_t)l,
      16, 0, 0);
}
template<bool HI>
__device__ __forceinline__ unsigned cvt2(float a, float b, unsigned old){
#if __has_builtin(__builtin_amdgcn_cvt_pk_fp8_f32)
  return (unsigned)__builtin_amdgcn_cvt_pk_fp8_f32(a, b, (int)old, HI);
#else
  __hip_fp8_e4m3 pa(a), pb(b);
  unsigned v = (unsigned)pa.__x | ((unsigned)pb.__x << 8);
  return HI ? ((old & 0x0000FFFFu) | (v << 16)) : ((old & 0xFFFF0000u) | v);
#endif
}
__device__ __forceinline__ void sync0(){
  asm volatile("s_waitcnt vmcnt(0) lgkmcnt(0)" ::: "memory");
  __builtin_amdgcn_s_barrier();
  __builtin_amdgcn_sched_barrier(0);
}

// ---------------- streaming convert: out_fp8 = fp8(in_f32 * scale) ----------------
__global__ __launch_bounds__(256) void k_cvt(const float* __restrict__ in,
                                             char* __restrict__ out,
                                             float scale, long n16){
  const long stride = (long)gridDim.x * 256;
  for (long i = (long)blockIdx.x * 256 + threadIdx.x; i < n16; i += stride){
    const f32x4* p = (const f32x4*)(in + i * 16);
    f32x4 a = __builtin_nontemporal_load(p);
    f32x4 b = __builtin_nontemporal_load(p + 1);
    f32x4 c = __builtin_nontemporal_load(p + 2);
    f32x4 d = __builtin_nontemporal_load(p + 3);
    u32x4 pk;
    pk[0] = cvt2<false>(a[0]*scale, a[1]*scale, 0u); pk[0] = cvt2<true>(a[2]*scale, a[3]*scale, pk[0]);
    pk[1] = cvt2<false>(b[0]*scale, b[1]*scale, 0u); pk[1] = cvt2<true>(b[2]*scale, b[3]*scale, pk[1]);
    pk[2] = cvt2<false>(c[0]*scale, c[1]*scale, 0u); pk[2] = cvt2<true>(c[2]*scale, c[3]*scale, pk[2]);
    pk[3] = cvt2<false>(d[0]*scale, d[1]*scale, 0u); pk[3] = cvt2<true>(d[2]*scale, d[3]*scale, pk[3]);
    *(u32x4*)(out + i * 16) = pk;   // normal store: keep fp8 copy L3-resident
  }
}

// ---------------- W0T[h][k] = fp8(W0[k][h]) ----------------
__global__ __launch_bounds__(256) void k_w0t(const float* __restrict__ W0,
                                             char* __restrict__ W0T){
  __shared__ float Ls[64][65];
  const int t = (int)threadIdx.x;
  const int k0 = (int)blockIdx.x * 64;
  const int h0 = (int)blockIdx.y * 64;
  {
    const int r = t >> 2, c = (t & 3) * 16;
    const float* p = W0 + (size_t)(k0 + r) * H1D + h0 + c;
#pragma unroll
    for (int q = 0; q < 4; ++q)
      *(float4*)&Ls[r][c + q*4] = *(const float4*)(p + q*4);
  }
  __syncthreads();
  const int h = t >> 2, kc = (t & 3) * 16;
  u32x4 pk;
#pragma unroll
  for (int q = 0; q < 4; ++q){
    unsigned wv = cvt2<false>(Ls[kc+q*4+0][h], Ls[kc+q*4+1][h], 0u);
    wv = cvt2<true>(Ls[kc+q*4+2][h], Ls[kc+q*4+3][h], wv);
    pk[q] = wv;
  }
  *(u32x4*)(W0T + (size_t)(h0 + h) * IND + k0 + kc) = pk;
}

// ------------- uniform fp8 GEMM (R7 config: 2-buffer, 3 blocks/CU) -------------
#define STAGE(BUF, SIDX) { \
  _Pragma("unroll") \
  for (int p = 0; p < 2; ++p) \
    gload_lds16(Ap + (size_t)(p*32) * lda + (size_t)(SIDX)*128, \
                Alds[BUF] + p*4096 + w*1024); \
  _Pragma("unroll") \
  for (int i = 0; i < 4; ++i) \
    gload_lds16(Bp + (size_t)(i*32) * ldb + (size_t)(SIDX)*128, \
                Blds[BUF] + i*4096 + w*1024); \
}

#define MF8(CUR) { \
  _Pragma("unroll") \
  for (int kk = 0; kk < 4; ++kk){ \
    long af[4]; long bfr[2]; \
    _Pragma("unroll") \
    for (int mi = 0; mi < 4; ++mi){ \
      int row = mi*16 + l15; \
      int off = row*128 + ((kk*32 + l16*8) ^ ((row & 7) << 4)); \
      af[mi] = *(const long*)(Alds[CUR] + off); \
    } \
    _Pragma("unroll") \
    for (int ni = 0; ni < 2; ++ni){ \
      int row = w*32 + ni*16 + l15; \
      int off = row*128 + ((kk*32 + l16*8) ^ ((row & 7) << 4)); \
      bfr[ni] = *(const long*)(Blds[CUR] + off); \
    } \
    _Pragma("unroll") \
    for (int mi = 0; mi < 4; ++mi) \
      _Pragma("unroll") \
      for (int ni = 0; ni < 2; ++ni) \
        acc[mi][ni] = __builtin_amdgcn_mfma_f32_16x16x32_fp8_fp8(af[mi], bfr[ni], acc[mi][ni], 0, 0, 0); \
  } }

template<int KSPLIT, int MODE>
__global__ __launch_bounds__(256, 3) void k_gf8(const char* __restrict__ A, int lda, int K,
                                                const char* __restrict__ Bt, int ldb,
                                                void* __restrict__ Out){
  __shared__ __align__(16) char Alds[2][64*128];
  __shared__ __align__(16) char Blds[2][128*128];
  const int t = (int)threadIdx.x;
  const int w = t >> 6, l = t & 63;
  const int l15 = l & 15, l16 = l >> 4;

  int khalf, idx;
  if (KSPLIT == 2){                 // XCDs 0-3 -> khalf 0, XCDs 4-7 -> khalf 1
    int f = (int)blockIdx.x, x = f & 7;
    khalf = x >> 2;
    idx = (f >> 3) * 4 + (x & 3);   // 0..383
  } else { khalf = 0; idx = (int)blockIdx.x; }
  const int m0 = (idx >> 1) * 64;
  const int nh = idx & 1;
  const size_t kb = (size_t)khalf * K;   // fp8: elements == bytes
  const int S = K >> 7;

  f32x4 acc[4][2];
#pragma unroll
  for (int mi = 0; mi < 4; ++mi)
#pragma unroll
    for (int ni = 0; ni < 2; ++ni) acc[mi][ni] = 0;

  // staging source pointers (T21: pre-swizzled global source, linear LDS dest)
  const int swz = ((l & 7) ^ (l >> 3)) << 4;
  const char* Ap = A  + (size_t)(m0 + w*8 + (l >> 3)) * lda + kb + swz;
  const char* Bp = Bt + (size_t)(nh*128 + w*8 + (l >> 3)) * ldb + kb + swz;

  STAGE(0, 0);
  sync0();
  for (int s = 0; s < S; ++s){
    const int cur = s & 1;
    if (s + 1 < S){ if (cur == 0){ STAGE(1, s + 1); } else { STAGE(0, s + 1); } }
    if (cur == 0){ MF8(0); } else { MF8(1); }
    if (s + 1 < S) sync0();
  }

  if (MODE == 0){
    char* OutT = (char*)Out;
#pragma unroll
    for (int mi = 0; mi < 4; ++mi)
#pragma unroll
      for (int ni = 0; ni < 2; ++ni){
        int gr = m0 + mi*16 + l16*4;
        int gc = nh*128 + w*32 + ni*16 + l15;
        unsigned wd = cvt2<false>(acc[mi][ni][0], acc[mi][ni][1], 0u);
        wd = cvt2<true>(acc[mi][ni][2], acc[mi][ni][3], wd);
        *(unsigned*)(OutT + (size_t)gc * NN + gr) = wd;
      }
  } else {
    float* P = (float*)Out + (size_t)khalf * NN * H1D;
#pragma unroll
    for (int mi = 0; mi < 4; ++mi)
#pragma unroll
      for (int ni = 0; ni < 2; ++ni){
        int gr = m0 + mi*16 + l16*4;
        int gc = nh*128 + w*32 + ni*16 + l15;
#pragma unroll
        for (int v = 0; v < 4; ++v)
          P[(size_t)(gr + v) * H1D + gc] = acc[mi][ni][v];
      }
  }
}

// ---------------- combine GEMM2 partials -> HidT[h][n] = fp8(relu(p0+p1)) (transposed) ----------------
__global__ __launch_bounds__(256) void k_combine_ht(const float* __restrict__ p0,
                                                    const float* __restrict__ p1,
                                                    char* __restrict__ HT){
  __shared__ float Ls[64][65];
  const int t = (int)threadIdx.x;
  const int n0 = (int)blockIdx.x * 64;
  const int h0 = (int)blockIdx.y * 64;
  const int lr = t >> 4, lc = (t & 15) * 4;
#pragma unroll
  for (int q = 0; q < 4; ++q){
    int n = lr + q*16;
    size_t idx = (size_t)(n0 + n) * H1D + h0 + lc;
    float4 a = *(const float4*)(p0 + idx);
    float4 b = *(const float4*)(p1 + idx);
    Ls[n][lc+0] = fmaxf(a.x + b.x, 0.f);
    Ls[n][lc+1] = fmaxf(a.y + b.y, 0.f);
    Ls[n][lc+2] = fmaxf(a.z + b.z, 0.f);
    Ls[n][lc+3] = fmaxf(a.w + b.w, 0.f);
  }
  __syncthreads();
  const int hr = t >> 2, nc = (t & 3) * 16;
  u32x4 pk;
#pragma unroll
  for (int q = 0; q < 4; ++q){
    unsigned wd = cvt2<false>(Ls[nc+q*4+0][hr], Ls[nc+q*4+1][hr], 0u);
    wd = cvt2<true>(Ls[nc+q*4+2][hr], Ls[nc+q*4+3][hr], wd);
    pk[q] = wd;
  }
  *(u32x4*)(HT + (size_t)(h0 + hr) * NN + n0 + nc) = pk;
}

// ---------------- heads (sums GEMM3 partials, x 2^-26) + reparam -> Zhi/Zlo ----------------
__global__ __launch_bounds__(256) void k_heads(const float* __restrict__ p0,
                                               const float* __restrict__ Wmu,
                                               const float* __restrict__ Wls,
                                               const float* __restrict__ noise,
                                               unsigned short* __restrict__ Zhi,
                                               unsigned short* __restrict__ Zlo){
  __shared__ float AHs[32][256];
  __shared__ float Wms[32][128];
  __shared__ float Wlss[32][128];
  const float INV = 1.0f / 67108864.0f;   // 2^-26 (undo S^2, S=2^13)
  const float* p1 = p0 + (size_t)NN * H1D;
  const int t  = (int)threadIdx.x;
  const int r0 = (int)blockIdx.x * 32;
  {
    const int r = t >> 3, c0 = (t & 7) * 32;
    size_t base = (size_t)(r0 + r) * H1D + c0;
#pragma unroll
    for (int q = 0; q < 8; ++q){
      float4 a = *(const float4*)(p0 + base + q*4);
      float4 b = *(const float4*)(p1 + base + q*4);
      AHs[r][c0 + q*4 + 0] = (a.x + b.x) * INV;
      AHs[r][c0 + q*4 + 1] = (a.y + b.y) * INV;
      AHs[r][c0 + q*4 + 2] = (a.z + b.z) * INV;
      AHs[r][c0 + q*4 + 3] = (a.w + b.w) * INV;
    }
  }
  const int j = t & 127, rg = t >> 7;
  float mu[16], ls[16];
#pragma unroll
  for (int r = 0; r < 16; ++r){ mu[r] = 0.f; ls[r] = 0.f; }

  for (int kc = 0; kc < 8; ++kc){
    __syncthreads();
    {
      const int r = t >> 3, c0 = (t & 7) * 16;
      const float* pm = Wmu + (size_t)(kc*32 + r) * H2D + c0;
      const float* pl = Wls + (size_t)(kc*32 + r) * H2D + c0;
#pragma unroll
      for (int q = 0; q < 4; ++q){
        *(float4*)&Wms[r][c0 + q*4]  = *(const float4*)(pm + q*4);
        *(float4*)&Wlss[r][c0 + q*4] = *(const float4*)(pl + q*4);
      }
    }
    __syncthreads();
#pragma unroll 4
    for (int k = 0; k < 32; ++k){
      float wm = Wms[k][j], wl = Wlss[k][j];
#pragma unroll
      for (int r = 0; r < 16; ++r){
        float a = AHs[rg*16 + r][kc*32 + k];
        mu[r] += a * wm;
        ls[r] += a * wl;
      }
    }
  }
#pragma unroll
  for (int r = 0; r < 16; ++r){
    const int i = r0 + rg*16 + r;
    float z = noise[(size_t)i * H2D + j] * __expf(ls[r]) + mu[r];
    unsigned short zh = f2bf(z);
    unsigned short zl = f2bf(z - bf2f(zh));
    Zhi[(size_t)i * H2D + j] = zh;
    Zlo[(size_t)i * H2D + j] = zl;
  }
}

// ---------------- decode: A_pred = sigmoid(Z @ Z^T), split-bf16, SYMMETRIC (upper-tri compute) ----------------
__global__ __launch_bounds__(512) void k_decode(const unsigned short* __restrict__ Zhi,
                                                const unsigned short* __restrict__ Zlo,
                                                float* __restrict__ Out){
  const int bx = (int)blockIdx.x, by = (int)blockIdx.y;
  if (by < bx) return;                       // lower-tri handled by mirror writes
  __shared__ __align__(16) char SMEM[65536];
  unsigned short* T0 = (unsigned short*)SMEM;            // 4 x 16KB Z tiles
  float (*Ls)[133] = (float(*)[133])SMEM;                // 64x133 transpose buf (34KB), reused after MFMA

  const int t = (int)threadIdx.x;
  const int w = t >> 6, l = t & 63;
  const int l15 = l & 15, l16 = l >> 4;
  const int wr = w >> 2, wc = w & 3;
  const size_t m0 = (size_t)bx * 128;
  const size_t n0 = (size_t)by * 128;

  f32x4 acc[4][2];
#pragma unroll
  for (int mi = 0; mi < 4; ++mi)
#pragma unroll
    for (int ni = 0; ni < 2; ++ni) acc[mi][ni] = 0;

#pragma unroll
  for (int p = 0; p < 2; ++p){
    if (p) __syncthreads();
#pragma unroll
    for (int i = 0; i < 2; ++i){
      int P = i*8192 + t*16;
      int row = P >> 7;
      int Li = (P & 127) ^ ((row & 7) << 4);
      size_t ga = (size_t)row * 256 + (size_t)p * 128 + Li;
      char* lb = (char*)T0 + i*8192 + w*1024;
      gload_lds16((const char*)Zhi + m0*256 + ga, lb);
      gload_lds16((const char*)Zlo + m0*256 + ga, lb + 16384);
      gload_lds16((const char*)Zhi + n0*256 + ga, lb + 32768);
      gload_lds16((const char*)Zlo + n0*256 + ga, lb + 49152);
    }
    __syncthreads();
#pragma unroll
    for (int kk = 0; kk < 2; ++kk){
      bf16x8 ah[4], al[4], bh[2], bl[2];
#pragma unroll
      for (int mi = 0; mi < 4; ++mi){
        int row = wr*64 + mi*16 + l15;
        int off = row*128 + ((kk*64 + l16*16) ^ ((row & 7) << 4));
        ah[mi] = *(const bf16x8*)((const char*)T0 + off);
        al[mi] = *(const bf16x8*)((const char*)T0 + 16384 + off);
      }
#pragma unroll
      for (int ni = 0; ni < 2; ++ni){
        int row = wc*32 + ni*16 + l15;
        int off = row*128 + ((kk*64 + l16*16) ^ ((row & 7) << 4));
        bh[ni] = *(const bf16x8*)((const char*)T0 + 32768 + off);
        bl[ni] = *(const bf16x8*)((const char*)T0 + 49152 + off);
      }
#pragma unroll
      for (int mi = 0; mi < 4; ++mi)
#pragma unroll
        for (int ni = 0; ni < 2; ++ni){
          acc[mi][ni] = __builtin_amdgcn_mfma_f32_16x16x32_bf16(ah[mi], bh[ni], acc[mi][ni], 0, 0, 0);
          acc[mi][ni] = __builtin_amdgcn_mfma_f32_16x16x32_bf16(ah[mi], bl[ni], acc[mi][ni], 0, 0, 0);
          acc[mi][ni] = __builtin_amdgcn_mfma_f32_16x16x32_bf16(al[mi], bh[ni], acc[mi][ni], 0, 0, 0);
        }
    }
  }

  // sigmoid in place, then normal (upper) write
#pragma unroll
  for (int mi = 0; mi < 4; ++mi)
#pragma unroll
    for (int ni = 0; ni < 2; ++ni){
      size_t gr = m0 + (size_t)(wr*64 + mi*16 + l16*4);
      size_t gc = n0 + (size_t)(wc*32 + ni*16 + l15);
#pragma unroll
      for (int v = 0; v < 4; ++v){
        float sg = 1.0f / (1.0f + __expf(-acc[mi][ni][v]));
        acc[mi][ni][v] = sg;
        __builtin_nontemporal_store(sg, &Out[(gr + v) * (size_t)NN + gc]);
      }
    }

  if (by == bx) return;

  // mirror write: transpose via LDS in two 64-row passes, coalesced stores
#pragma unroll
  for (int p = 0; p < 2; ++p){
    __syncthreads();                 // Ls reuses T0 memory / previous pass
    if (wr == p){
#pragma unroll
      for (int mi = 0; mi < 4; ++mi)
#pragma unroll
        for (int ni = 0; ni < 2; ++ni)
#pragma unroll
          for (int v = 0; v < 4; ++v)
            Ls[mi*16 + l16*4 + v][wc*32 + ni*16 + l15] = acc[mi][ni][v];
    }
    __syncthreads();
    const int a = t >> 2;            // mirror row (= original col), 0..127
    const int b0 = (t & 3) * 16;     // mirror col group (= original row-64p), 0..63
    float vv[16];
#pragma unroll
    for (int k = 0; k < 16; ++k) vv[k] = Ls[b0 + k][a];
    float* dst = &Out[(n0 + a) * (size_t)NN + m0 + (size_t)(p*64 + b0)];
#pragma unroll
    for (int q = 0; q < 4; ++q){
      f32x4 pk = { vv[q*4+0], vv[q*4+1], vv[q*4+2], vv[q*4+3] };
      __builtin_nontemporal_store(pk, (f32x4*)(dst + q*4));
    }
  }
}

extern "C" void kernel_launch(void* const* d_in, const int* in_sizes, int n_in,
                              void* d_out, int out_size, void* d_ws, size_t ws_size,
                              hipStream_t stream) {
  const float* X     = (const float*)d_in[0];
  const float* adj   = (const float*)d_in[1];
  const float* noise = (const float*)d_in[2];
  const float* W0    = (const float*)d_in[3];
  const float* Wmu   = (const float*)d_in[4];
  const float* Wls   = (const float*)d_in[5];
  float* out = (float*)d_out;
  char* ws = (char*)d_ws;

  // small arrays in ws
  char*           XW0Tf8 = ws;                                  // 3145728
  char*           HidTf8 = ws + 3145728;                        // 3145728
  char*           W0Tf8  = ws + 6291456;                        // 131072
  unsigned short* Zhi    = (unsigned short*)(ws + 6422528);     // 3145728
  unsigned short* Zlo    = (unsigned short*)(ws + 9568256);     // 3145728
  char*           Xf8    = ws + 12713984;                       // 6291456
  // big scratch in d_out (dead until decode): adj_fp8 151 MB + partials 25 MB
  char*  adjf8 = (char*)d_out;                                  // 150994944
  float* part  = (float*)((char*)d_out + 150994944);            // 25165824

  const float S_ADJ = 8192.0f;   // 2^13; heads divides by 2^26

  k_cvt<<<2048, 256, 0, stream>>>(adj, adjf8, S_ADJ, (long)NN * NN / 16);
  k_w0t<<<dim3(8, 4), 256, 0, stream>>>(W0, W0Tf8);
  k_cvt<<<256, 256, 0, stream>>>(X, Xf8, 1.0f, (long)NN * IND / 16);
  k_gf8<1,0><<<384, 256, 0, stream>>>(Xf8, IND, IND, W0Tf8, IND, (void*)XW0Tf8);
  k_gf8<2,1><<<768, 256, 0, stream>>>(adjf8, NN, 6144, XW0Tf8, NN, (void*)part);
  k_combine_ht<<<dim3(192, 4), 256, 0, stream>>>(part, part + (size_t)NN * H1D, HidTf8);
  k_gf8<2,1><<<768, 256, 0, stream>>>(adjf8, NN, 6144, HidTf8, NN, (void*)part);
  k_heads<<<384, 256, 0, stream>>>(part, Wmu, Wls, noise, Zhi, Zlo);
  k_decode<<<dim3(96, 96), 512, 0, stream>>>(Zhi, Zlo, out);
}

// Round 10
// 605.232 us; speedup vs baseline: 1.5230x; 1.5230x over previous
//
#include <hip/hip_runtime.h>
#include <hip/hip_fp8.h>
#include <stdint.h>

#define NN 12288
#define IND 512
#define H1D 256
#define H2D 128

using bf16x8 = __attribute__((ext_vector_type(8))) short;
using f32x4  = __attribute__((ext_vector_type(4))) float;
using u32x4  = __attribute__((ext_vector_type(4))) unsigned int;

__device__ __forceinline__ unsigned short f2bf(float f){
  unsigned int u = __float_as_uint(f);
  return (unsigned short)((u + 0x7fffu + ((u >> 16) & 1u)) >> 16);
}
__device__ __forceinline__ float bf2f(unsigned short h){
  return __uint_as_float(((unsigned int)h) << 16);
}
__device__ __forceinline__ void gload_lds16(const void* g, void* l){
  __builtin_amdgcn_global_load_lds(
      (const __attribute__((address_space(1))) unsigned int*)(uintptr_t)g,
      (__attribute__((address_space(3))) unsigned int*)(unsigned int)(uintptr_t)l,
      16, 0, 0);
}
template<bool HI>
__device__ __forceinline__ unsigned cvt2(float a, float b, unsigned old){
#if __has_builtin(__builtin_amdgcn_cvt_pk_fp8_f32)
  return (unsigned)__builtin_amdgcn_cvt_pk_fp8_f32(a, b, (int)old, HI);
#else
  __hip_fp8_e4m3 pa(a), pb(b);
  unsigned v = (unsigned)pa.__x | ((unsigned)pb.__x << 8);
  return HI ? ((old & 0x0000FFFFu) | (v << 16)) : ((old & 0xFFFF0000u) | v);
#endif
}
__device__ __forceinline__ void sync0(){
  asm volatile("s_waitcnt vmcnt(0) lgkmcnt(0)" ::: "memory");
  __builtin_amdgcn_s_barrier();
  __builtin_amdgcn_sched_barrier(0);
}

// ---------------- streaming convert: out_fp8 = fp8(in_f32 * scale) ----------------
__global__ __launch_bounds__(256) void k_cvt(const float* __restrict__ in,
                                             char* __restrict__ out,
                                             float scale, long n16){
  const long stride = (long)gridDim.x * 256;
  for (long i = (long)blockIdx.x * 256 + threadIdx.x; i < n16; i += stride){
    const f32x4* p = (const f32x4*)(in + i * 16);
    f32x4 a = __builtin_nontemporal_load(p);
    f32x4 b = __builtin_nontemporal_load(p + 1);
    f32x4 c = __builtin_nontemporal_load(p + 2);
    f32x4 d = __builtin_nontemporal_load(p + 3);
    u32x4 pk;
    pk[0] = cvt2<false>(a[0]*scale, a[1]*scale, 0u); pk[0] = cvt2<true>(a[2]*scale, a[3]*scale, pk[0]);
    pk[1] = cvt2<false>(b[0]*scale, b[1]*scale, 0u); pk[1] = cvt2<true>(b[2]*scale, b[3]*scale, pk[1]);
    pk[2] = cvt2<false>(c[0]*scale, c[1]*scale, 0u); pk[2] = cvt2<true>(c[2]*scale, c[3]*scale, pk[2]);
    pk[3] = cvt2<false>(d[0]*scale, d[1]*scale, 0u); pk[3] = cvt2<true>(d[2]*scale, d[3]*scale, pk[3]);
    *(u32x4*)(out + i * 16) = pk;   // normal store: keep fp8 copy L3-resident
  }
}

// ---------------- W0T[h][k] = fp8(W0[k][h]) ----------------
__global__ __launch_bounds__(256) void k_w0t(const float* __restrict__ W0,
                                             char* __restrict__ W0T){
  __shared__ float Ls[64][65];
  const int t = (int)threadIdx.x;
  const int k0 = (int)blockIdx.x * 64;
  const int h0 = (int)blockIdx.y * 64;
  {
    const int r = t >> 2, c = (t & 3) * 16;
    const float* p = W0 + (size_t)(k0 + r) * H1D + h0 + c;
#pragma unroll
    for (int q = 0; q < 4; ++q)
      *(float4*)&Ls[r][c + q*4] = *(const float4*)(p + q*4);
  }
  __syncthreads();
  const int h = t >> 2, kc = (t & 3) * 16;
  u32x4 pk;
#pragma unroll
  for (int q = 0; q < 4; ++q){
    unsigned wv = cvt2<false>(Ls[kc+q*4+0][h], Ls[kc+q*4+1][h], 0u);
    wv = cvt2<true>(Ls[kc+q*4+2][h], Ls[kc+q*4+3][h], wv);
    pk[q] = wv;
  }
  *(u32x4*)(W0T + (size_t)(h0 + h) * IND + k0 + kc) = pk;
}

// ------------- uniform fp8 GEMM (R7 config: 2-buffer, 3 blocks/CU) -------------
#define STAGE(BUF, SIDX) { \
  _Pragma("unroll") \
  for (int p = 0; p < 2; ++p) \
    gload_lds16(Ap + (size_t)(p*32) * lda + (size_t)(SIDX)*128, \
                Alds[BUF] + p*4096 + w*1024); \
  _Pragma("unroll") \
  for (int i = 0; i < 4; ++i) \
    gload_lds16(Bp + (size_t)(i*32) * ldb + (size_t)(SIDX)*128, \
                Blds[BUF] + i*4096 + w*1024); \
}

#define MF8(CUR) { \
  _Pragma("unroll") \
  for (int kk = 0; kk < 4; ++kk){ \
    long af[4]; long bfr[2]; \
    _Pragma("unroll") \
    for (int mi = 0; mi < 4; ++mi){ \
      int row = mi*16 + l15; \
      int off = row*128 + ((kk*32 + l16*8) ^ ((row & 7) << 4)); \
      af[mi] = *(const long*)(Alds[CUR] + off); \
    } \
    _Pragma("unroll") \
    for (int ni = 0; ni < 2; ++ni){ \
      int row = w*32 + ni*16 + l15; \
      int off = row*128 + ((kk*32 + l16*8) ^ ((row & 7) << 4)); \
      bfr[ni] = *(const long*)(Blds[CUR] + off); \
    } \
    _Pragma("unroll") \
    for (int mi = 0; mi < 4; ++mi) \
      _Pragma("unroll") \
      for (int ni = 0; ni < 2; ++ni) \
        acc[mi][ni] = __builtin_amdgcn_mfma_f32_16x16x32_fp8_fp8(af[mi], bfr[ni], acc[mi][ni], 0, 0, 0); \
  } }

template<int KSPLIT, int MODE>
__global__ __launch_bounds__(256, 3) void k_gf8(const char* __restrict__ A, int lda, int K,
                                                const char* __restrict__ Bt, int ldb,
                                                void* __restrict__ Out){
  __shared__ __align__(16) char Alds[2][64*128];
  __shared__ __align__(16) char Blds[2][128*128];
  const int t = (int)threadIdx.x;
  const int w = t >> 6, l = t & 63;
  const int l15 = l & 15, l16 = l >> 4;

  int khalf, idx;
  if (KSPLIT == 2){                 // XCDs 0-3 -> khalf 0, XCDs 4-7 -> khalf 1
    int f = (int)blockIdx.x, x = f & 7;
    khalf = x >> 2;
    idx = (f >> 3) * 4 + (x & 3);   // 0..383
  } else { khalf = 0; idx = (int)blockIdx.x; }
  const int m0 = (idx >> 1) * 64;
  const int nh = idx & 1;
  const size_t kb = (size_t)khalf * K;   // fp8: elements == bytes
  const int S = K >> 7;

  f32x4 acc[4][2];
#pragma unroll
  for (int mi = 0; mi < 4; ++mi)
#pragma unroll
    for (int ni = 0; ni < 2; ++ni) acc[mi][ni] = 0;

  // staging source pointers (T21: pre-swizzled global source, linear LDS dest)
  const int swz = ((l & 7) ^ (l >> 3)) << 4;
  const char* Ap = A  + (size_t)(m0 + w*8 + (l >> 3)) * lda + kb + swz;
  const char* Bp = Bt + (size_t)(nh*128 + w*8 + (l >> 3)) * ldb + kb + swz;

  STAGE(0, 0);
  sync0();
  for (int s = 0; s < S; ++s){
    const int cur = s & 1;
    if (s + 1 < S){ if (cur == 0){ STAGE(1, s + 1); } else { STAGE(0, s + 1); } }
    if (cur == 0){ MF8(0); } else { MF8(1); }
    if (s + 1 < S) sync0();
  }

  if (MODE == 0){
    char* OutT = (char*)Out;
#pragma unroll
    for (int mi = 0; mi < 4; ++mi)
#pragma unroll
      for (int ni = 0; ni < 2; ++ni){
        int gr = m0 + mi*16 + l16*4;
        int gc = nh*128 + w*32 + ni*16 + l15;
        unsigned wd = cvt2<false>(acc[mi][ni][0], acc[mi][ni][1], 0u);
        wd = cvt2<true>(acc[mi][ni][2], acc[mi][ni][3], wd);
        *(unsigned*)(OutT + (size_t)gc * NN + gr) = wd;
      }
  } else {
    float* P = (float*)Out + (size_t)khalf * NN * H1D;
#pragma unroll
    for (int mi = 0; mi < 4; ++mi)
#pragma unroll
      for (int ni = 0; ni < 2; ++ni){
        int gr = m0 + mi*16 + l16*4;
        int gc = nh*128 + w*32 + ni*16 + l15;
#pragma unroll
        for (int v = 0; v < 4; ++v)
          P[(size_t)(gr + v) * H1D + gc] = acc[mi][ni][v];
      }
  }
}

// ---------------- combine GEMM2 partials -> HidT[h][n] = fp8(relu(p0+p1)) (transposed) ----------------
__global__ __launch_bounds__(256) void k_combine_ht(const float* __restrict__ p0,
                                                    const float* __restrict__ p1,
                                                    char* __restrict__ HT){
  __shared__ float Ls[64][65];
  const int t = (int)threadIdx.x;
  const int n0 = (int)blockIdx.x * 64;
  const int h0 = (int)blockIdx.y * 64;
  const int lr = t >> 4, lc = (t & 15) * 4;
#pragma unroll
  for (int q = 0; q < 4; ++q){
    int n = lr + q*16;
    size_t idx = (size_t)(n0 + n) * H1D + h0 + lc;
    float4 a = *(const float4*)(p0 + idx);
    float4 b = *(const float4*)(p1 + idx);
    Ls[n][lc+0] = fmaxf(a.x + b.x, 0.f);
    Ls[n][lc+1] = fmaxf(a.y + b.y, 0.f);
    Ls[n][lc+2] = fmaxf(a.z + b.z, 0.f);
    Ls[n][lc+3] = fmaxf(a.w + b.w, 0.f);
  }
  __syncthreads();
  const int hr = t >> 2, nc = (t & 3) * 16;
  u32x4 pk;
#pragma unroll
  for (int q = 0; q < 4; ++q){
    unsigned wd = cvt2<false>(Ls[nc+q*4+0][hr], Ls[nc+q*4+1][hr], 0u);
    wd = cvt2<true>(Ls[nc+q*4+2][hr], Ls[nc+q*4+3][hr], wd);
    pk[q] = wd;
  }
  *(u32x4*)(HT + (size_t)(h0 + hr) * NN + n0 + nc) = pk;
}

// ---------------- heads (sums GEMM3 partials, x 2^-26) + reparam -> Zhi/Zlo ----------------
__global__ __launch_bounds__(256) void k_heads(const float* __restrict__ p0,
                                               const float* __restrict__ Wmu,
                                               const float* __restrict__ Wls,
                                               const float* __restrict__ noise,
                                               unsigned short* __restrict__ Zhi,
                                               unsigned short* __restrict__ Zlo){
  __shared__ float AHs[32][256];
  __shared__ float Wms[32][128];
  __shared__ float Wlss[32][128];
  const float INV = 1.0f / 67108864.0f;   // 2^-26 (undo S^2, S=2^13)
  const float* p1 = p0 + (size_t)NN * H1D;
  const int t  = (int)threadIdx.x;
  const int r0 = (int)blockIdx.x * 32;
  {
    const int r = t >> 3, c0 = (t & 7) * 32;
    size_t base = (size_t)(r0 + r) * H1D + c0;
#pragma unroll
    for (int q = 0; q < 8; ++q){
      float4 a = *(const float4*)(p0 + base + q*4);
      float4 b = *(const float4*)(p1 + base + q*4);
      AHs[r][c0 + q*4 + 0] = (a.x + b.x) * INV;
      AHs[r][c0 + q*4 + 1] = (a.y + b.y) * INV;
      AHs[r][c0 + q*4 + 2] = (a.z + b.z) * INV;
      AHs[r][c0 + q*4 + 3] = (a.w + b.w) * INV;
    }
  }
  const int j = t & 127, rg = t >> 7;
  float mu[16], ls[16];
#pragma unroll
  for (int r = 0; r < 16; ++r){ mu[r] = 0.f; ls[r] = 0.f; }

  for (int kc = 0; kc < 8; ++kc){
    __syncthreads();
    {
      const int r = t >> 3, c0 = (t & 7) * 16;
      const float* pm = Wmu + (size_t)(kc*32 + r) * H2D + c0;
      const float* pl = Wls + (size_t)(kc*32 + r) * H2D + c0;
#pragma unroll
      for (int q = 0; q < 4; ++q){
        *(float4*)&Wms[r][c0 + q*4]  = *(const float4*)(pm + q*4);
        *(float4*)&Wlss[r][c0 + q*4] = *(const float4*)(pl + q*4);
      }
    }
    __syncthreads();
#pragma unroll 4
    for (int k = 0; k < 32; ++k){
      float wm = Wms[k][j], wl = Wlss[k][j];
#pragma unroll
      for (int r = 0; r < 16; ++r){
        float a = AHs[rg*16 + r][kc*32 + k];
        mu[r] += a * wm;
        ls[r] += a * wl;
      }
    }
  }
#pragma unroll
  for (int r = 0; r < 16; ++r){
    const int i = r0 + rg*16 + r;
    float z = noise[(size_t)i * H2D + j] * __expf(ls[r]) + mu[r];
    unsigned short zh = f2bf(z);
    unsigned short zl = f2bf(z - bf2f(zh));
    Zhi[(size_t)i * H2D + j] = zh;
    Zlo[(size_t)i * H2D + j] = zl;
  }
}

// ---------------- decode: A_pred = sigmoid(Z @ Z^T), symmetric, LDS-coalesced epilogue ----------------
__global__ __launch_bounds__(512, 2) void k_decode(const unsigned short* __restrict__ Zhi,
                                                   const unsigned short* __restrict__ Zlo,
                                                   float* __restrict__ Out){
  __shared__ __align__(16) char SMEM[65536];
  unsigned short* T0 = (unsigned short*)SMEM;            // 4 x 16KB Z tiles (MFMA phase)
  float (*Ls)[133] = (float(*)[133])SMEM;                // 64x133 f32 staging (epilogue), reuses SMEM

  // triangular block mapping: i -> (bx <= by)
  const int i = (int)blockIdx.x;
  int by = (int)((sqrtf(8.0f * (float)i + 1.0f) - 1.0f) * 0.5f);
  while ((by + 1) * (by + 2) / 2 <= i) ++by;
  while (by * (by + 1) / 2 > i) --by;
  const int bx = i - by * (by + 1) / 2;
  const bool diag = (bx == by);

  const int t = (int)threadIdx.x;
  const int w = t >> 6, l = t & 63;
  const int l15 = l & 15, l16 = l >> 4;
  const int wr = w >> 2, wc = w & 3;
  const size_t m0 = (size_t)bx * 128;
  const size_t n0 = (size_t)by * 128;

  f32x4 acc[4][2];
#pragma unroll
  for (int mi = 0; mi < 4; ++mi)
#pragma unroll
    for (int ni = 0; ni < 2; ++ni) acc[mi][ni] = 0;

#pragma unroll
  for (int p = 0; p < 2; ++p){
    if (p) __syncthreads();
#pragma unroll
    for (int i2 = 0; i2 < 2; ++i2){
      int P = i2*8192 + t*16;
      int row = P >> 7;
      int Li = (P & 127) ^ ((row & 7) << 4);
      size_t ga = (size_t)row * 256 + (size_t)p * 128 + Li;
      char* lb = (char*)T0 + i2*8192 + w*1024;
      gload_lds16((const char*)Zhi + m0*256 + ga, lb);
      gload_lds16((const char*)Zlo + m0*256 + ga, lb + 16384);
      gload_lds16((const char*)Zhi + n0*256 + ga, lb + 32768);
      gload_lds16((const char*)Zlo + n0*256 + ga, lb + 49152);
    }
    __syncthreads();
#pragma unroll
    for (int kk = 0; kk < 2; ++kk){
      bf16x8 ah[4], al[4], bh[2], bl[2];
#pragma unroll
      for (int mi = 0; mi < 4; ++mi){
        int row = wr*64 + mi*16 + l15;
        int off = row*128 + ((kk*64 + l16*16) ^ ((row & 7) << 4));
        ah[mi] = *(const bf16x8*)((const char*)T0 + off);
        al[mi] = *(const bf16x8*)((const char*)T0 + 16384 + off);
      }
#pragma unroll
      for (int ni = 0; ni < 2; ++ni){
        int row = wc*32 + ni*16 + l15;
        int off = row*128 + ((kk*64 + l16*16) ^ ((row & 7) << 4));
        bh[ni] = *(const bf16x8*)((const char*)T0 + 32768 + off);
        bl[ni] = *(const bf16x8*)((const char*)T0 + 49152 + off);
      }
#pragma unroll
      for (int mi = 0; mi < 4; ++mi)
#pragma unroll
        for (int ni = 0; ni < 2; ++ni){
          acc[mi][ni] = __builtin_amdgcn_mfma_f32_16x16x32_bf16(ah[mi], bh[ni], acc[mi][ni], 0, 0, 0);
          acc[mi][ni] = __builtin_amdgcn_mfma_f32_16x16x32_bf16(ah[mi], bl[ni], acc[mi][ni], 0, 0, 0);
          acc[mi][ni] = __builtin_amdgcn_mfma_f32_16x16x32_bf16(al[mi], bh[ni], acc[mi][ni], 0, 0, 0);
        }
    }
  }

  // epilogue: two row-half passes through LDS; all stores are coalesced f32x4
#pragma unroll
  for (int p = 0; p < 2; ++p){
    __syncthreads();
    if (wr == p){
#pragma unroll
      for (int mi = 0; mi < 4; ++mi)
#pragma unroll
        for (int ni = 0; ni < 2; ++ni)
#pragma unroll
          for (int v = 0; v < 4; ++v){
            float sg = 1.0f / (1.0f + __expf(-acc[mi][ni][v]));
            Ls[mi*16 + l16*4 + v][wc*32 + ni*16 + l15] = sg;
          }
    }
    __syncthreads();
    {
      // upper tile rows m0+p*64+r, full 512B row segments
      const int r = t >> 3, c0 = (t & 7) * 16;
      float* dst = &Out[(m0 + (size_t)(p*64 + r)) * NN + n0 + c0];
      const float* src = &Ls[r][c0];
#pragma unroll
      for (int q = 0; q < 4; ++q)
        *(f32x4*)(dst + q*4) = *(const f32x4*)(src + q*4);
    }
    if (!diag){
      // mirror tile: rows n0+a, cols m0+p*64+b0 (transposed read from Ls)
      const int a = t >> 2, b0 = (t & 3) * 16;
      float vv[16];
#pragma unroll
      for (int k = 0; k < 16; ++k) vv[k] = Ls[b0 + k][a];
      float* dst = &Out[(n0 + (size_t)a) * NN + m0 + (size_t)(p*64 + b0)];
#pragma unroll
      for (int q = 0; q < 4; ++q){
        f32x4 pk = { vv[q*4+0], vv[q*4+1], vv[q*4+2], vv[q*4+3] };
        *(f32x4*)(dst + q*4) = pk;
      }
    }
  }
}

extern "C" void kernel_launch(void* const* d_in, const int* in_sizes, int n_in,
                              void* d_out, int out_size, void* d_ws, size_t ws_size,
                              hipStream_t stream) {
  const float* X     = (const float*)d_in[0];
  const float* adj   = (const float*)d_in[1];
  const float* noise = (const float*)d_in[2];
  const float* W0    = (const float*)d_in[3];
  const float* Wmu   = (const float*)d_in[4];
  const float* Wls   = (const float*)d_in[5];
  float* out = (float*)d_out;
  char* ws = (char*)d_ws;

  // small arrays in ws
  char*           XW0Tf8 = ws;                                  // 3145728
  char*           HidTf8 = ws + 3145728;                        // 3145728
  char*           W0Tf8  = ws + 6291456;                        // 131072
  unsigned short* Zhi    = (unsigned short*)(ws + 6422528);     // 3145728
  unsigned short* Zlo    = (unsigned short*)(ws + 9568256);     // 3145728
  char*           Xf8    = ws + 12713984;                       // 6291456
  // big scratch in d_out (dead until decode): adj_fp8 151 MB + partials 25 MB
  char*  adjf8 = (char*)d_out;                                  // 150994944
  float* part  = (float*)((char*)d_out + 150994944);            // 25165824

  const float S_ADJ = 8192.0f;   // 2^13; heads divides by 2^26

  k_cvt<<<2048, 256, 0, stream>>>(adj, adjf8, S_ADJ, (long)NN * NN / 16);
  k_w0t<<<dim3(8, 4), 256, 0, stream>>>(W0, W0Tf8);
  k_cvt<<<256, 256, 0, stream>>>(X, Xf8, 1.0f, (long)NN * IND / 16);
  k_gf8<1,0><<<384, 256, 0, stream>>>(Xf8, IND, IND, W0Tf8, IND, (void*)XW0Tf8);
  k_gf8<2,1><<<768, 256, 0, stream>>>(adjf8, NN, 6144, XW0Tf8, NN, (void*)part);
  k_combine_ht<<<dim3(192, 4), 256, 0, stream>>>(part, part + (size_t)NN * H1D, HidTf8);
  k_gf8<2,1><<<768, 256, 0, stream>>>(adjf8, NN, 6144, HidTf8, NN, (void*)part);
  k_heads<<<384, 256, 0, stream>>>(part, Wmu, Wls, noise, Zhi, Zlo);
  k_decode<<<4656, 512, 0, stream>>>(Zhi, Zlo, out);
}